// Round 1
// baseline (75.766 us; speedup 1.0000x reference)
//
#include <hip/hip_runtime.h>

// EMA scan: out[:,0]=x[:,0]; out[:,i]=0.9*out[:,i-1]+0.1*x[:,i]
// x: [32, 4096, 256] f32.  Output: out (33554432 f32) ++ tail (32 f32, out[b,4095,0]).
//
// Chunked 2-pass linear-recurrence scan:
//  pass1: per (b, chunk, cgroup) compute chunk-local scan end value (carry) -> ws
//  pass2: per (b, cgroup) sequential scan of 64 chunk carries (in-place: slot k
//         becomes the incoming prefix for chunk k), transfer factor alpha^64
//  pass3: recompute chunk-local scan seeded with prefix, write out + tail.

#define B_  32
#define T_  4096
#define C_  256
#define CG  64     // C/4 float4 groups
#define L_  64     // chunk length
#define NC  64     // T_/L_ chunks

#define ALPHA 0.9f
#define OMA   0.1f // 1 - ALPHA

static constexpr float alpha_pow_l() {
    double r = 1.0;
    for (int i = 0; i < L_; ++i) r *= 0.9;
    return (float)r;
}

__device__ __forceinline__ float4 ema_step(float4 y, float4 v) {
    float4 r;
    r.x = fmaf(ALPHA, y.x, OMA * v.x);
    r.y = fmaf(ALPHA, y.y, OMA * v.y);
    r.z = fmaf(ALPHA, y.z, OMA * v.z);
    r.w = fmaf(ALPHA, y.w, OMA * v.w);
    return r;
}

// ---- pass 1: chunk-local carries ---------------------------------------
__global__ __launch_bounds__(256) void ema_pass1(const float* __restrict__ x,
                                                 float4* __restrict__ carry) {
    int tid   = blockIdx.x * blockDim.x + threadIdx.x; // (b*NC + chunk)*CG + cg
    int cg    = tid & (CG - 1);
    int bc    = tid >> 6;          // b*NC + chunk
    int chunk = bc & (NC - 1);
    int b     = bc >> 6;

    const float4* xp = reinterpret_cast<const float4*>(x)
                     + (size_t)(b * T_ + chunk * L_) * CG + cg;

    float4 acc;
    if (chunk == 0) {              // wave-uniform branch
        acc = xp[0];               // y_0 = x_0 exactly
        #pragma unroll 8
        for (int j = 1; j < L_; ++j) {
            float4 v = xp[(size_t)j * CG];
            acc = ema_step(acc, v);
        }
    } else {
        acc = make_float4(0.f, 0.f, 0.f, 0.f);
        #pragma unroll 8
        for (int j = 0; j < L_; ++j) {
            float4 v = xp[(size_t)j * CG];
            acc = ema_step(acc, v);
        }
    }
    carry[bc * CG + cg] = acc;
}

// ---- pass 2: scan carries across chunks (in place) ---------------------
__global__ __launch_bounds__(256) void ema_pass2(float4* __restrict__ cp) {
    int tid = blockIdx.x * blockDim.x + threadIdx.x; // b*CG + cg, 2048 total
    int cg  = tid & (CG - 1);
    int b   = tid >> 6;
    const float aL = alpha_pow_l();

    float4 p = make_float4(0.f, 0.f, 0.f, 0.f);
    for (int k = 0; k < NC; ++k) {
        int idx  = (b * NC + k) * CG + cg;
        float4 c = cp[idx];
        cp[idx]  = p;              // incoming prefix for chunk k
        if (k == 0) {
            p = c;                 // chunk 0 local scan is already exact
        } else {
            p.x = fmaf(aL, p.x, c.x);
            p.y = fmaf(aL, p.y, c.y);
            p.z = fmaf(aL, p.z, c.z);
            p.w = fmaf(aL, p.w, c.w);
        }
    }
}

// ---- pass 3: final scan with prefixes, write out + tail ----------------
__global__ __launch_bounds__(256) void ema_pass3(const float* __restrict__ x,
                                                 const float4* __restrict__ prefix,
                                                 float* __restrict__ out,
                                                 float* __restrict__ tail) {
    int tid   = blockIdx.x * blockDim.x + threadIdx.x;
    int cg    = tid & (CG - 1);
    int bc    = tid >> 6;
    int chunk = bc & (NC - 1);
    int b     = bc >> 6;

    size_t base = (size_t)(b * T_ + chunk * L_) * CG + cg;
    const float4* xp = reinterpret_cast<const float4*>(x) + base;
    float4*       op = reinterpret_cast<float4*>(out) + base;

    float4 y = prefix[bc * CG + cg];
    if (chunk == 0) {
        y = xp[0];
        op[0] = y;
        #pragma unroll 8
        for (int j = 1; j < L_; ++j) {
            float4 v = xp[(size_t)j * CG];
            y = ema_step(y, v);
            op[(size_t)j * CG] = y;
        }
    } else {
        #pragma unroll 8
        for (int j = 0; j < L_; ++j) {
            float4 v = xp[(size_t)j * CG];
            y = ema_step(y, v);
            op[(size_t)j * CG] = y;
        }
    }
    if (chunk == NC - 1 && cg == 0) {
        tail[b] = y.x;             // out[b, T-1, 0]
    }
}

extern "C" void kernel_launch(void* const* d_in, const int* in_sizes, int n_in,
                              void* d_out, int out_size, void* d_ws, size_t ws_size,
                              hipStream_t stream) {
    const float* x = (const float*)d_in[0];
    float* out  = (float*)d_out;
    float* tail = out + (size_t)B_ * T_ * C_;   // 33554432
    float4* ws  = (float4*)d_ws;                // needs B_*NC*CG*16B = 2 MiB

    int threads1 = B_ * NC * CG;                // 131072
    ema_pass1<<<threads1 / 256, 256, 0, stream>>>(x, ws);
    ema_pass2<<<(B_ * CG) / 256, 256, 0, stream>>>(ws);
    ema_pass3<<<threads1 / 256, 256, 0, stream>>>(x, ws, out, tail);
}

// Round 3
// 70.680 us; speedup vs baseline: 1.0720x; 1.0720x over previous
//
#include <hip/hip_runtime.h>

// EMA scan: out[:,0]=x[:,0]; out[:,i]=0.9*out[:,i-1]+0.1*x[:,i]
// x: [32, 4096, 256] f32.  Output: out (33554432 f32) ++ tail (32 f32, out[b,4095,0]).
//
// 2-kernel chunked scan:
//  pass1: per (b, chunk, cgroup) compute chunk-local zero-seeded scan end value
//         (carry) -> ws.  x loads are NORMAL (we want x resident in L3).
//  pass3: each thread redundantly folds its prefix from the carry array
//         (L2/L3-resident, wave-uniform trip count), rescans its chunk reading
//         x from L3, and writes out with NON-TEMPORAL stores (native clang
//         vector type — __builtin_nontemporal_store rejects HIP float4) so the
//         128 MB of out traffic does not evict x from L3 mid-pass.

#define B_  32
#define T_  4096
#define C_  256
#define CG  64     // C/4 float4 groups
#define L_  64     // chunk length
#define NC  64     // T_/L_ chunks

#define ALPHA 0.9f
#define OMA   0.1f // 1 - ALPHA

typedef float f32x4 __attribute__((ext_vector_type(4)));

static constexpr float alpha_pow_l() {
    double r = 1.0;
    for (int i = 0; i < L_; ++i) r *= 0.9;
    return (float)r;
}

__device__ __forceinline__ f32x4 ema_step(f32x4 y, f32x4 v) {
    f32x4 r;
    r.x = fmaf(ALPHA, y.x, OMA * v.x);
    r.y = fmaf(ALPHA, y.y, OMA * v.y);
    r.z = fmaf(ALPHA, y.z, OMA * v.z);
    r.w = fmaf(ALPHA, y.w, OMA * v.w);
    return r;
}

// ---- pass 1: chunk-local carries ---------------------------------------
__global__ __launch_bounds__(256) void ema_pass1(const float* __restrict__ x,
                                                 f32x4* __restrict__ carry) {
    int tid   = blockIdx.x * blockDim.x + threadIdx.x; // (b*NC + chunk)*CG + cg
    int cg    = tid & (CG - 1);
    int bc    = tid >> 6;          // b*NC + chunk
    int chunk = bc & (NC - 1);
    int b     = bc >> 6;

    const f32x4* xp = reinterpret_cast<const f32x4*>(x)
                    + (size_t)(b * T_ + chunk * L_) * CG + cg;

    f32x4 acc;
    if (chunk == 0) {              // wave-uniform branch
        acc = xp[0];               // y_0 = x_0 exactly
        #pragma unroll 8
        for (int j = 1; j < L_; ++j) {
            f32x4 v = xp[(size_t)j * CG];
            acc = ema_step(acc, v);
        }
    } else {
        acc = (f32x4)(0.f);
        #pragma unroll 8
        for (int j = 0; j < L_; ++j) {
            f32x4 v = xp[(size_t)j * CG];
            acc = ema_step(acc, v);
        }
    }
    carry[bc * CG + cg] = acc;
}

// ---- pass 3: fold prefix from carries, rescan, nt-store out ------------
__global__ __launch_bounds__(256) void ema_pass3(const float* __restrict__ x,
                                                 const f32x4* __restrict__ carry,
                                                 float* __restrict__ out,
                                                 float* __restrict__ tail) {
    int tid   = blockIdx.x * blockDim.x + threadIdx.x;
    int cg    = tid & (CG - 1);
    int bc    = tid >> 6;
    int chunk = bc & (NC - 1);
    int b     = bc >> 6;

    size_t base = (size_t)(b * T_ + chunk * L_) * CG + cg;
    const f32x4* xp = reinterpret_cast<const f32x4*>(x) + base;
    f32x4*       op = reinterpret_cast<f32x4*>(out) + base;

    f32x4 y;
    if (chunk == 0) {              // wave-uniform
        y = xp[0];
        __builtin_nontemporal_store(y, &op[0]);
        #pragma unroll 8
        for (int j = 1; j < L_; ++j) {
            f32x4 v = xp[(size_t)j * CG];
            y = ema_step(y, v);
            __builtin_nontemporal_store(y, &op[(size_t)j * CG]);
        }
    } else {
        // redundant per-thread prefix fold over this sequence's carries
        // (wave-uniform trip count; 16B loads from the hot 2 MB carry array)
        const f32x4* cp = carry + (size_t)b * NC * CG + cg;
        const float aL = alpha_pow_l();
        f32x4 p = cp[0];
        #pragma unroll 4
        for (int k = 1; k < chunk; ++k) {
            f32x4 c = cp[(size_t)k * CG];
            p.x = fmaf(aL, p.x, c.x);
            p.y = fmaf(aL, p.y, c.y);
            p.z = fmaf(aL, p.z, c.z);
            p.w = fmaf(aL, p.w, c.w);
        }
        y = p;
        #pragma unroll 8
        for (int j = 0; j < L_; ++j) {
            f32x4 v = xp[(size_t)j * CG];
            y = ema_step(y, v);
            __builtin_nontemporal_store(y, &op[(size_t)j * CG]);
        }
    }
    if (chunk == NC - 1 && cg == 0) {
        tail[b] = y.x;             // out[b, T-1, 0]
    }
}

extern "C" void kernel_launch(void* const* d_in, const int* in_sizes, int n_in,
                              void* d_out, int out_size, void* d_ws, size_t ws_size,
                              hipStream_t stream) {
    const float* x = (const float*)d_in[0];
    float* out  = (float*)d_out;
    float* tail = out + (size_t)B_ * T_ * C_;   // 33554432
    f32x4* ws   = (f32x4*)d_ws;                 // needs B_*NC*CG*16B = 2 MiB

    int threads = B_ * NC * CG;                 // 131072
    ema_pass1<<<threads / 256, 256, 0, stream>>>(x, ws);
    ema_pass3<<<threads / 256, 256, 0, stream>>>(x, ws, out, tail);
}